// Round 18
// baseline (163.653 us; speedup 1.0000x reference)
//
#include <hip/hip_runtime.h>
#include <math.h>

#define L_SEQ 4096
#define D_HEAD 64
#define M_WIN 128
#define WIN 257              // 2*M+1
#define QB 8                 // q rows per block
#define W 264                // WIN + QB - 1
#define WF4 66               // W/4
#define ATTS 272             // att row stride (bf16 elements); uint2 stride 68
#define SCALE 0.125f         // 1/sqrt(64)

// wave-uniform lane read via VALU (v_readlane -> SGPR), not LDS pipe
#define RL(v, i) __uint_as_float(__builtin_amdgcn_readlane(__float_as_uint(v), (i)))

static __device__ __forceinline__ unsigned bfr(float x) {      // f32->bf16 RNE
    unsigned u = __float_as_uint(x);
    return (u + 0x7fffu + ((u >> 16) & 1u)) >> 16;
}
static __device__ __forceinline__ unsigned bfpack(float lo, float hi) {
    return bfr(lo) | (bfr(hi) << 16);
}
static __device__ __forceinline__ float bf2f(unsigned h) {     // bf16->f32
    return __uint_as_float(h << 16);
}

// K tile: [264 rows][8 uint4 slots], slot = c8 ^ (row&7); one uint4 = 8 bf16.
// att tile: [QB][272] bf16 -> total LDS 38144 B -> 4 blocks/CU.
// Phase E+D fused: dense-row stores interleaved into the PV loop so the
// store stream runs during compute (stores issue AFTER the V loads consumed
// later -> counted vmcnt only, no drain; stores retire at L2-accept).
__global__ __launch_bounds__(256, 4) void win_attn_kernel(
    const float* __restrict__ Q, const float* __restrict__ K,
    const float* __restrict__ V, float* __restrict__ OutO,
    float* __restrict__ OutA)
{
    extern __shared__ float smem[];
    uint4*  k_su  = (uint4*)smem;            // [264][8] uint4 = 33792 B
    unsigned short* att_h = (unsigned short*)(smem + 2112 * 4);  // [QB][ATTS]

    const int t  = threadIdx.x;
    const int w  = t >> 6;                   // wave 0..3 -> q rows {2w, 2w+1}
    const int ln = t & 63;
    const int bid = blockIdx.x;              // native mapping
    const int b   = bid >> 9;
    const int q0  = (bid & 511) * QB;

    int s0 = q0 - M_WIN;
    if (s0 < 0) s0 = 0;
    if (s0 > L_SEQ - WIN) s0 = L_SEQ - WIN;
    const int wcount = (L_SEQ - s0 < W) ? (L_SEQ - s0) : W;

    // ---------------- Phase A: stage K (bf16, swizzled); q rows -> registers
    {
        const float4* Kg = (const float4*)(K + ((size_t)(b * L_SEQ + s0)) * D_HEAD);
        #pragma unroll 3
        for (int idx = t; idx < 264 * 8; idx += 256) {
            int row = idx >> 3, c8 = idx & 7;
            int gr  = (row < wcount) ? row : wcount - 1;
            float4 a  = Kg[(size_t)gr * 16 + c8 * 2];
            float4 bb = Kg[(size_t)gr * 16 + c8 * 2 + 1];
            uint4 d;
            d.x = bfpack(a.x, a.y);   d.y = bfpack(a.z, a.w);
            d.z = bfpack(bb.x, bb.y); d.w = bfpack(bb.z, bb.w);
            k_su[row * 8 + (c8 ^ (row & 7))] = d;
        }
    }
    const int r0g = q0 + 2 * w;              // this wave's two global q rows
    const float qv0 = Q[((size_t)(b * L_SEQ) + r0g)     * D_HEAD + ln];
    const float qv1 = Q[((size_t)(b * L_SEQ) + r0g + 1) * D_HEAD + ln];
    // zero the att row pad (cols 264..271) for vectorized phase E reads
    if (ln < 16) {
        int r = 2 * w + (ln >> 3);
        att_h[r * ATTS + 264 + (ln & 7)] = 0;
    }
    __syncthreads();                         // the ONLY block-wide barrier

    // ---------------- Phase B: scores; lane owns cols cg*64+ln --------------
    float p0[5], p1[5];
    {
        const uint4* kp[5];
        int msk[5];
        #pragma unroll
        for (int cg = 0; cg < 5; ++cg) {
            int colr = cg * 64 + ln;
            int col  = (colr < W) ? colr : W - 1;   // clamped for memory
            kp[cg]  = k_su + (size_t)col * 8;
            msk[cg] = col & 7;
            p0[cg] = 0.f; p1[cg] = 0.f;
        }
        #pragma unroll
        for (int c8 = 0; c8 < 8; ++c8) {
            float a0 = RL(qv0, 8*c8+0), a1 = RL(qv0, 8*c8+1),
                  a2 = RL(qv0, 8*c8+2), a3 = RL(qv0, 8*c8+3),
                  a4 = RL(qv0, 8*c8+4), a5 = RL(qv0, 8*c8+5),
                  a6 = RL(qv0, 8*c8+6), a7 = RL(qv0, 8*c8+7);
            float b0 = RL(qv1, 8*c8+0), b1 = RL(qv1, 8*c8+1),
                  b2 = RL(qv1, 8*c8+2), b3 = RL(qv1, 8*c8+3),
                  b4 = RL(qv1, 8*c8+4), b5 = RL(qv1, 8*c8+5),
                  b6 = RL(qv1, 8*c8+6), b7 = RL(qv1, 8*c8+7);
            #pragma unroll
            for (int cg = 0; cg < 5; ++cg) {
                uint4 kk = kp[cg][c8 ^ msk[cg]];
                float e0 = __uint_as_float(kk.x << 16);
                float e1 = __uint_as_float(kk.x & 0xffff0000u);
                float e2 = __uint_as_float(kk.y << 16);
                float e3 = __uint_as_float(kk.y & 0xffff0000u);
                float e4 = __uint_as_float(kk.z << 16);
                float e5 = __uint_as_float(kk.z & 0xffff0000u);
                float e6 = __uint_as_float(kk.w << 16);
                float e7 = __uint_as_float(kk.w & 0xffff0000u);
                p0[cg] += a0*e0 + a1*e1 + a2*e2 + a3*e3
                        + a4*e4 + a5*e5 + a6*e6 + a7*e7;
                p1[cg] += b0*e0 + b1*e1 + b2*e2 + b3*e3
                        + b4*e4 + b5*e5 + b6*e6 + b7*e7;
            }
        }
        #pragma unroll
        for (int cg = 0; cg < 5; ++cg) { p0[cg] *= SCALE; p1[cg] *= SCALE; }
    }

    // ---------------- Phase C: in-register masked softmax (per wave) --------
    {
        int st0 = r0g - M_WIN;
        if (st0 < 0) st0 = 0;
        if (st0 > L_SEQ - WIN) st0 = L_SEQ - WIN;
        const int lo0 = st0 - s0;
        int st1 = r0g + 1 - M_WIN;
        if (st1 < 0) st1 = 0;
        if (st1 > L_SEQ - WIN) st1 = L_SEQ - WIN;
        const int lo1 = st1 - s0;

        float m0 = -1e30f, m1 = -1e30f;
        #pragma unroll
        for (int cg = 0; cg < 5; ++cg) {
            int colr = cg * 64 + ln;
            bool in0 = (colr >= lo0) && (colr < lo0 + WIN);
            bool in1 = (colr >= lo1) && (colr < lo1 + WIN);
            p0[cg] = in0 ? p0[cg] : -1e30f;
            p1[cg] = in1 ? p1[cg] : -1e30f;
            m0 = fmaxf(m0, p0[cg]);
            m1 = fmaxf(m1, p1[cg]);
        }
        #pragma unroll
        for (int off = 32; off >= 1; off >>= 1) {
            m0 = fmaxf(m0, __shfl_xor(m0, off));
            m1 = fmaxf(m1, __shfl_xor(m1, off));
        }
        float sum0 = 0.f, sum1 = 0.f;
        #pragma unroll
        for (int cg = 0; cg < 5; ++cg) {
            float e0 = (p0[cg] <= -1e29f) ? 0.f : __expf(p0[cg] - m0);
            float e1 = (p1[cg] <= -1e29f) ? 0.f : __expf(p1[cg] - m1);
            p0[cg] = e0; p1[cg] = e1;
            sum0 += e0; sum1 += e1;
        }
        #pragma unroll
        for (int off = 32; off >= 1; off >>= 1) {
            sum0 += __shfl_xor(sum0, off);
            sum1 += __shfl_xor(sum1, off);
        }
        const float inv0 = 1.f / sum0, inv1 = 1.f / sum1;
        #pragma unroll
        for (int cg = 0; cg < 5; ++cg) {
            int colr = cg * 64 + ln;
            if (colr < W) {
                att_h[(2 * w)     * ATTS + colr] = (unsigned short)bfr(p0[cg] * inv0);
                att_h[(2 * w + 1) * ATTS + colr] = (unsigned short)bfr(p1[cg] * inv1);
            }
        }
    }
    // No barrier: everything below reads only this wave's own att rows.

    // ---------------- Phase E+D fused: PV with interleaved dense stores -----
    {
        const int cq = ln >> 4;              // which 4-col group of 16
        const int dg = ln & 15;              // d float4-group
        const bool aligned = ((s0 & 3) == 0);
        const int zlo = s0 >> 2;
        const float4* Vg4 = (const float4*)(V + ((size_t)(b * L_SEQ + s0)) * D_HEAD);
        const uint2* a2r0 = (const uint2*)(att_h + (2 * w) * ATTS);
        const uint2* a2r1 = (const uint2*)(att_h + (2 * w + 1) * ATTS);
        float4* rowp0 = (float4*)(OutA + ((size_t)(b * L_SEQ + r0g))     * L_SEQ);
        float4* rowp1 = (float4*)(OutA + ((size_t)(b * L_SEQ + r0g + 1)) * L_SEQ);
        float4 acc0 = {0.f,0.f,0.f,0.f}, acc1 = {0.f,0.f,0.f,0.f};
        #pragma unroll 1
        for (int G = 0; G < 17; ++G) {       // 17*16 = 272 cols (pad p = 0)
            uint2 ua = a2r0[4 * G + cq];     // 4 bf16 p-values
            uint2 ub = a2r1[4 * G + cq];
            float pa[4], pb[4];
            pa[0] = bf2f(ua.x & 0xffffu); pa[1] = bf2f(ua.x >> 16);
            pa[2] = bf2f(ua.y & 0xffffu); pa[3] = bf2f(ua.y >> 16);
            pb[0] = bf2f(ub.x & 0xffffu); pb[1] = bf2f(ub.x >> 16);
            pb[2] = bf2f(ub.y & 0xffffu); pb[3] = bf2f(ub.y >> 16);
            #pragma unroll
            for (int e = 0; e < 4; ++e) {
                int col  = 16 * G + 4 * cq + e;
                int colc = (col < wcount) ? col : wcount - 1;   // p is 0 there
                float4 vv = Vg4[(size_t)colc * 16 + dg];
                float fa = pa[e], fb = pb[e];
                acc0.x += fa * vv.x; acc0.y += fa * vv.y;
                acc0.z += fa * vv.z; acc0.w += fa * vv.w;
                acc1.x += fb * vv.x; acc1.y += fb * vv.y;
                acc1.z += fb * vv.z; acc1.w += fb * vv.w;
            }
            // interleaved dense store, j = G (issued AFTER this iter's loads)
            if (aligned && G < 16) {
                int f4i = G * 64 + ln;
                int u4  = f4i - zlo;
                float4 w0 = {0.f,0.f,0.f,0.f}, w1 = {0.f,0.f,0.f,0.f};
                if (u4 >= 0 && u4 < WF4) {
                    uint2 uu0 = a2r0[u4];
                    uint2 uu1 = a2r1[u4];
                    w0.x = bf2f(uu0.x & 0xffffu); w0.y = bf2f(uu0.x >> 16);
                    w0.z = bf2f(uu0.y & 0xffffu); w0.w = bf2f(uu0.y >> 16);
                    w1.x = bf2f(uu1.x & 0xffffu); w1.y = bf2f(uu1.x >> 16);
                    w1.z = bf2f(uu1.y & 0xffffu); w1.w = bf2f(uu1.y >> 16);
                }
                rowp0[f4i] = w0;
                rowp1[f4i] = w1;
            }
        }
        #pragma unroll
        for (int off = 16; off <= 32; off <<= 1) {
            acc0.x += __shfl_xor(acc0.x, off); acc0.y += __shfl_xor(acc0.y, off);
            acc0.z += __shfl_xor(acc0.z, off); acc0.w += __shfl_xor(acc0.w, off);
            acc1.x += __shfl_xor(acc1.x, off); acc1.y += __shfl_xor(acc1.y, off);
            acc1.z += __shfl_xor(acc1.z, off); acc1.w += __shfl_xor(acc1.w, off);
        }
        if (ln < 16) {
            float4* o4 = (float4*)(OutO + ((size_t)(b * L_SEQ + r0g)) * D_HEAD);
            o4[dg]      = acc0;
            o4[16 + dg] = acc1;
        }

        // rare top-edge blocks (s0 = 3839): separate scalar-gather store pass
        if (!aligned) {
            #pragma unroll
            for (int r = 0; r < 2; ++r) {
                float4* rowp = (r == 0) ? rowp0 : rowp1;
                const unsigned short* arow = att_h + (2 * w + r) * ATTS;
                #pragma unroll 2
                for (int j = 0; j < 16; ++j) {
                    int f4i = j * 64 + ln;
                    int u   = 4 * f4i - s0;
                    float4 wv;
                    wv.x = (u     >= 0 && u     < W) ? bf2f(arow[u])     : 0.f;
                    wv.y = (u + 1 >= 0 && u + 1 < W) ? bf2f(arow[u + 1]) : 0.f;
                    wv.z = (u + 2 >= 0 && u + 2 < W) ? bf2f(arow[u + 2]) : 0.f;
                    wv.w = (u + 3 >= 0 && u + 3 < W) ? bf2f(arow[u + 3]) : 0.f;
                    rowp[f4i] = wv;
                }
            }
        }
    }
}

extern "C" void kernel_launch(void* const* d_in, const int* in_sizes, int n_in,
                              void* d_out, int out_size, void* d_ws, size_t ws_size,
                              hipStream_t stream) {
    const float* Q = (const float*)d_in[0];
    const float* K = (const float*)d_in[1];
    const float* V = (const float*)d_in[2];
    float* OutO = (float*)d_out;
    float* OutA = OutO + (size_t)8 * L_SEQ * D_HEAD;

    const int smem_bytes = 2112 * 16 + QB * ATTS * 2;   // 38144 B -> 4 blk/CU
    hipFuncSetAttribute((const void*)win_attn_kernel,
                        hipFuncAttributeMaxDynamicSharedMemorySize, smem_bytes);

    dim3 grid(8 * (L_SEQ / QB));    // 4096 blocks
    dim3 block(256);
    win_attn_kernel<<<grid, block, smem_bytes, stream>>>(Q, K, V, OutO, OutA);
}

// Round 19
// 149.752 us; speedup vs baseline: 1.0928x; 1.0928x over previous
//
#include <hip/hip_runtime.h>
#include <math.h>

#define L_SEQ 4096
#define D_HEAD 64
#define M_WIN 128
#define WIN 257              // 2*M+1
#define QB 8                 // q rows per tile
#define NT 2                 // tiles per block
#define QBLK 16              // q rows per block
#define KROWS 272            // staged K rows (covers both tiles' windows)
#define W 264                // per-tile window union
#define WF4 66               // W/4
#define ATTS 272             // att row stride (bf16 elements); uint2 stride 68
#define SCALE 0.125f         // 1/sqrt(64)

// wave-uniform lane read via VALU (v_readlane -> SGPR), not LDS pipe
#define RL(v, i) __uint_as_float(__builtin_amdgcn_readlane(__float_as_uint(v), (i)))

static __device__ __forceinline__ unsigned bfr(float x) {      // f32->bf16 RNE
    unsigned u = __float_as_uint(x);
    return (u + 0x7fffu + ((u >> 16) & 1u)) >> 16;
}
static __device__ __forceinline__ unsigned bfpack(float lo, float hi) {
    return bfr(lo) | (bfr(hi) << 16);
}
static __device__ __forceinline__ float bf2f(unsigned h) {     // bf16->f32
    return __uint_as_float(h << 16);
}

// K tile: [272 rows][8 uint4 slots], slot = c8 ^ (row&7); one uint4 = 8 bf16.
// att tile: [QB][272] bf16. Total LDS 39168 B -> 4 blocks/CU.
// NT=2 q-tiles share one staged K window -> K/V fetch demand halves.
__global__ __launch_bounds__(256, 4) void win_attn_kernel(
    const float* __restrict__ Q, const float* __restrict__ K,
    const float* __restrict__ V, float* __restrict__ OutO,
    float* __restrict__ OutA)
{
    extern __shared__ float smem[];
    uint4*  k_su  = (uint4*)smem;            // [272][8] uint4 = 34816 B
    unsigned short* att_h = (unsigned short*)(smem + 8704);   // [QB][ATTS] bf16

    const int t  = threadIdx.x;
    const int w  = t >> 6;                   // wave 0..3 -> rows {2w,2w+1}/tile
    const int ln = t & 63;
    const int bid = blockIdx.x;              // native mapping
    const int b      = bid >> 8;             // 256 blocks per batch
    const int q0_blk = (bid & 255) * QBLK;

    int s0_blk = q0_blk - M_WIN;
    if (s0_blk < 0) s0_blk = 0;
    if (s0_blk > L_SEQ - KROWS) s0_blk = L_SEQ - KROWS;   // <= 3824

    // ---------------- Phase A: stage 272-row K window (bf16, swizzled) ------
    {
        const float4* Kg = (const float4*)(K + ((size_t)(b * L_SEQ + s0_blk)) * D_HEAD);
        #pragma unroll 3
        for (int idx = t; idx < KROWS * 8; idx += 256) {
            int row = idx >> 3, c8 = idx & 7;               // rows all in-bounds
            float4 a  = Kg[(size_t)row * 16 + c8 * 2];
            float4 bb = Kg[(size_t)row * 16 + c8 * 2 + 1];
            uint4 d;
            d.x = bfpack(a.x, a.y);   d.y = bfpack(a.z, a.w);
            d.z = bfpack(bb.x, bb.y); d.w = bfpack(bb.z, bb.w);
            k_su[row * 8 + (c8 ^ (row & 7))] = d;
        }
    }
    // both tiles' q rows -> registers (before barrier; no stores in flight)
    float qv[NT][2];
    #pragma unroll
    for (int ti = 0; ti < NT; ++ti) {
        int rg = q0_blk + ti * QB + 2 * w;
        qv[ti][0] = Q[((size_t)(b * L_SEQ) + rg)     * D_HEAD + ln];
        qv[ti][1] = Q[((size_t)(b * L_SEQ) + rg + 1) * D_HEAD + ln];
    }
    // zero the att row pad (cols 264..271) for vectorized phase E reads
    if (ln < 16) {
        int r = 2 * w + (ln >> 3);
        att_h[r * ATTS + 264 + (ln & 7)] = 0;
    }
    __syncthreads();                         // the ONLY block-wide barrier

    // ---------------- NT tiles, wave-private after staging ------------------
    #pragma unroll
    for (int ti = 0; ti < NT; ++ti) {
        const int q0  = q0_blk + ti * QB;
        const int r0g = q0 + 2 * w;
        int s0 = q0 - M_WIN;
        if (s0 < 0) s0 = 0;
        if (s0 > L_SEQ - WIN) s0 = L_SEQ - WIN;
        const int off    = s0 - s0_blk;      // 0..15; off+wcount <= 272
        const int wcount = (L_SEQ - s0 < W) ? (L_SEQ - s0) : W;
        const float qv0 = qv[ti][0], qv1 = qv[ti][1];

        // ---------------- Phase B: scores; lane owns cols cg*64+ln ----------
        float p0[5], p1[5];
        {
            const uint4* kp[5];
            int msk[5];
            #pragma unroll
            for (int cg = 0; cg < 5; ++cg) {
                int colr = cg * 64 + ln;
                int col  = (colr < wcount) ? colr : wcount - 1;
                int row  = off + col;        // <= 271, in staged range
                kp[cg]  = k_su + (size_t)row * 8;
                msk[cg] = row & 7;
                p0[cg] = 0.f; p1[cg] = 0.f;
            }
            #pragma unroll
            for (int c8 = 0; c8 < 8; ++c8) {
                float a0 = RL(qv0, 8*c8+0), a1 = RL(qv0, 8*c8+1),
                      a2 = RL(qv0, 8*c8+2), a3 = RL(qv0, 8*c8+3),
                      a4 = RL(qv0, 8*c8+4), a5 = RL(qv0, 8*c8+5),
                      a6 = RL(qv0, 8*c8+6), a7 = RL(qv0, 8*c8+7);
                float b0 = RL(qv1, 8*c8+0), b1 = RL(qv1, 8*c8+1),
                      b2 = RL(qv1, 8*c8+2), b3 = RL(qv1, 8*c8+3),
                      b4 = RL(qv1, 8*c8+4), b5 = RL(qv1, 8*c8+5),
                      b6 = RL(qv1, 8*c8+6), b7 = RL(qv1, 8*c8+7);
                #pragma unroll
                for (int cg = 0; cg < 5; ++cg) {
                    uint4 kk = kp[cg][c8 ^ msk[cg]];
                    float e0 = __uint_as_float(kk.x << 16);
                    float e1 = __uint_as_float(kk.x & 0xffff0000u);
                    float e2 = __uint_as_float(kk.y << 16);
                    float e3 = __uint_as_float(kk.y & 0xffff0000u);
                    float e4 = __uint_as_float(kk.z << 16);
                    float e5 = __uint_as_float(kk.z & 0xffff0000u);
                    float e6 = __uint_as_float(kk.w << 16);
                    float e7 = __uint_as_float(kk.w & 0xffff0000u);
                    p0[cg] += a0*e0 + a1*e1 + a2*e2 + a3*e3
                            + a4*e4 + a5*e5 + a6*e6 + a7*e7;
                    p1[cg] += b0*e0 + b1*e1 + b2*e2 + b3*e3
                            + b4*e4 + b5*e5 + b6*e6 + b7*e7;
                }
            }
            #pragma unroll
            for (int cg = 0; cg < 5; ++cg) { p0[cg] *= SCALE; p1[cg] *= SCALE; }
        }

        // ---------------- Phase C: in-register masked softmax ---------------
        {
            int st0 = r0g - M_WIN;
            if (st0 < 0) st0 = 0;
            if (st0 > L_SEQ - WIN) st0 = L_SEQ - WIN;
            const int lo0 = st0 - s0;
            int st1 = r0g + 1 - M_WIN;
            if (st1 < 0) st1 = 0;
            if (st1 > L_SEQ - WIN) st1 = L_SEQ - WIN;
            const int lo1 = st1 - s0;

            float m0 = -1e30f, m1 = -1e30f;
            #pragma unroll
            for (int cg = 0; cg < 5; ++cg) {
                int colr = cg * 64 + ln;
                bool in0 = (colr >= lo0) && (colr < lo0 + WIN);
                bool in1 = (colr >= lo1) && (colr < lo1 + WIN);
                p0[cg] = in0 ? p0[cg] : -1e30f;
                p1[cg] = in1 ? p1[cg] : -1e30f;
                m0 = fmaxf(m0, p0[cg]);
                m1 = fmaxf(m1, p1[cg]);
            }
            #pragma unroll
            for (int o = 32; o >= 1; o >>= 1) {
                m0 = fmaxf(m0, __shfl_xor(m0, o));
                m1 = fmaxf(m1, __shfl_xor(m1, o));
            }
            float sum0 = 0.f, sum1 = 0.f;
            #pragma unroll
            for (int cg = 0; cg < 5; ++cg) {
                float e0 = (p0[cg] <= -1e29f) ? 0.f : __expf(p0[cg] - m0);
                float e1 = (p1[cg] <= -1e29f) ? 0.f : __expf(p1[cg] - m1);
                p0[cg] = e0; p1[cg] = e1;
                sum0 += e0; sum1 += e1;
            }
            #pragma unroll
            for (int o = 32; o >= 1; o >>= 1) {
                sum0 += __shfl_xor(sum0, o);
                sum1 += __shfl_xor(sum1, o);
            }
            const float inv0 = 1.f / sum0, inv1 = 1.f / sum1;
            #pragma unroll
            for (int cg = 0; cg < 5; ++cg) {
                int colr = cg * 64 + ln;
                if (colr < W) {
                    att_h[(2 * w)     * ATTS + colr] = (unsigned short)bfr(p0[cg] * inv0);
                    att_h[(2 * w + 1) * ATTS + colr] = (unsigned short)bfr(p1[cg] * inv1);
                }
            }
        }
        // No barrier: E/D read only this wave's own att rows (in-order LDS);
        // next tile's C overwrites them only after this tile's E/D complete.

        // ---------------- Phase E: PV; b64 att reads ------------------------
        {
            const int cq = ln >> 4;
            const int dg = ln & 15;
            const float4* Vg4 = (const float4*)(V + ((size_t)(b * L_SEQ + s0)) * D_HEAD);
            const uint2* a2r0 = (const uint2*)(att_h + (2 * w) * ATTS);
            const uint2* a2r1 = (const uint2*)(att_h + (2 * w + 1) * ATTS);
            float4 acc0 = {0.f,0.f,0.f,0.f}, acc1 = {0.f,0.f,0.f,0.f};
            #pragma unroll 2
            for (int G = 0; G < 17; ++G) {   // 272 cols (pad p = 0)
                uint2 ua = a2r0[4 * G + cq];
                uint2 ub = a2r1[4 * G + cq];
                float pa[4], pb[4];
                pa[0] = bf2f(ua.x & 0xffffu); pa[1] = bf2f(ua.x >> 16);
                pa[2] = bf2f(ua.y & 0xffffu); pa[3] = bf2f(ua.y >> 16);
                pb[0] = bf2f(ub.x & 0xffffu); pb[1] = bf2f(ub.x >> 16);
                pb[2] = bf2f(ub.y & 0xffffu); pb[3] = bf2f(ub.y >> 16);
                #pragma unroll
                for (int e = 0; e < 4; ++e) {
                    int col  = 16 * G + 4 * cq + e;
                    int colc = (col < wcount) ? col : wcount - 1;  // p 0 there
                    float4 vv = Vg4[(size_t)colc * 16 + dg];
                    float fa = pa[e], fb = pb[e];
                    acc0.x += fa * vv.x; acc0.y += fa * vv.y;
                    acc0.z += fa * vv.z; acc0.w += fa * vv.w;
                    acc1.x += fb * vv.x; acc1.y += fb * vv.y;
                    acc1.z += fb * vv.z; acc1.w += fb * vv.w;
                }
            }
            #pragma unroll
            for (int o = 16; o <= 32; o <<= 1) {
                acc0.x += __shfl_xor(acc0.x, o); acc0.y += __shfl_xor(acc0.y, o);
                acc0.z += __shfl_xor(acc0.z, o); acc0.w += __shfl_xor(acc0.w, o);
                acc1.x += __shfl_xor(acc1.x, o); acc1.y += __shfl_xor(acc1.y, o);
                acc1.z += __shfl_xor(acc1.z, o); acc1.w += __shfl_xor(acc1.w, o);
            }
            if (ln < 16) {
                float4* o4 = (float4*)(OutO + ((size_t)(b * L_SEQ + r0g)) * D_HEAD);
                o4[dg]      = acc0;
                o4[16 + dg] = acc1;
            }
        }

        // ---------------- Phase D: dense stream of this wave's 2 att rows ---
        if ((s0 & 3) == 0) {
            const int zlo = s0 >> 2;
            #pragma unroll
            for (int r = 0; r < 2; ++r) {
                float4* rowp = (float4*)(OutA + ((size_t)(b * L_SEQ + r0g + r)) * L_SEQ);
                const uint2* arow = (const uint2*)(att_h + (2 * w + r) * ATTS);
                #pragma unroll 4
                for (int j = 0; j < 16; ++j) {
                    int f4i = j * 64 + ln;
                    int u4  = f4i - zlo;
                    float4 wv = {0.f,0.f,0.f,0.f};
                    if (u4 >= 0 && u4 < WF4) {
                        uint2 uu = arow[u4];
                        wv.x = bf2f(uu.x & 0xffffu); wv.y = bf2f(uu.x >> 16);
                        wv.z = bf2f(uu.y & 0xffffu); wv.w = bf2f(uu.y >> 16);
                    }
                    rowp[f4i] = wv;
                }
            }
        } else {   // top-edge tiles (s0 = 3839)
            #pragma unroll
            for (int r = 0; r < 2; ++r) {
                float4* rowp = (float4*)(OutA + ((size_t)(b * L_SEQ + r0g + r)) * L_SEQ);
                const unsigned short* arow = att_h + (2 * w + r) * ATTS;
                #pragma unroll 2
                for (int j = 0; j < 16; ++j) {
                    int f4i = j * 64 + ln;
                    int u   = 4 * f4i - s0;
                    float4 wv;
                    wv.x = (u     >= 0 && u     < W) ? bf2f(arow[u])     : 0.f;
                    wv.y = (u + 1 >= 0 && u + 1 < W) ? bf2f(arow[u + 1]) : 0.f;
                    wv.z = (u + 2 >= 0 && u + 2 < W) ? bf2f(arow[u + 2]) : 0.f;
                    wv.w = (u + 3 >= 0 && u + 3 < W) ? bf2f(arow[u + 3]) : 0.f;
                    rowp[f4i] = wv;
                }
            }
        }
    }
}

extern "C" void kernel_launch(void* const* d_in, const int* in_sizes, int n_in,
                              void* d_out, int out_size, void* d_ws, size_t ws_size,
                              hipStream_t stream) {
    const float* Q = (const float*)d_in[0];
    const float* K = (const float*)d_in[1];
    const float* V = (const float*)d_in[2];
    float* OutO = (float*)d_out;
    float* OutA = OutO + (size_t)8 * L_SEQ * D_HEAD;

    const int smem_bytes = KROWS * 128 + QB * ATTS * 2;   // 39168 B -> 4 blk/CU
    hipFuncSetAttribute((const void*)win_attn_kernel,
                        hipFuncAttributeMaxDynamicSharedMemorySize, smem_bytes);

    dim3 grid(8 * (L_SEQ / QBLK));   // 2048 blocks = 2 clean generations
    dim3 block(256);
    win_attn_kernel<<<grid, block, smem_bytes, stream>>>(Q, K, V, OutO, OutA);
}